// Round 1
// baseline (1052.105 us; speedup 1.0000x reference)
//
#include <hip/hip_runtime.h>

// ---------------------------------------------------------------------------
// 2-layer GCN forward on MI355X.
// Strategy: build CSR (by dst) once per call, then per layer:
//   h = x @ W^T            (dense, W staged in LDS, one wave = one row x4)
//   out[i] = sum_{e: dst=e} norm_e * h[src_e] + dinv[i]^2 * h[i] + b  (+relu)
// One wave per node, lane == channel (64 channels == 64 lanes).
// ---------------------------------------------------------------------------

static inline size_t align_up(size_t x, size_t a) { return (x + a - 1) & ~(a - 1); }

__global__ void k_init_counts(int* counts, int n) {
    int i = blockIdx.x * blockDim.x + threadIdx.x;
    if (i < n) counts[i] = 0;
}

__global__ void k_hist(const int* __restrict__ dst, int* counts, int E) {
    int e = blockIdx.x * blockDim.x + threadIdx.x;
    if (e < E) atomicAdd(&counts[dst[e]], 1);
}

__global__ void k_dinv(const int* __restrict__ counts, float* dinv, int n) {
    int i = blockIdx.x * blockDim.x + threadIdx.x;
    if (i < n) dinv[i] = rsqrtf((float)(counts[i] + 1));  // +1 self-loop
}

// --- two-level exclusive scan of counts -> row offsets --------------------
__global__ void k_scan1(const int* __restrict__ counts, int* row_off,
                        int* blocksum, int n) {
    __shared__ int s[256];
    int i = blockIdx.x * 256 + threadIdx.x;
    int v = (i < n) ? counts[i] : 0;
    s[threadIdx.x] = v;
    __syncthreads();
    for (int off = 1; off < 256; off <<= 1) {
        int t = (threadIdx.x >= off) ? s[threadIdx.x - off] : 0;
        __syncthreads();
        s[threadIdx.x] += t;
        __syncthreads();
    }
    if (i < n) row_off[i + 1] = s[threadIdx.x];  // inclusive, block-local
    if (threadIdx.x == 255) blocksum[blockIdx.x] = s[255];
}

__global__ void k_scan2(const int* __restrict__ blocksum, int* blockoffs, int nb) {
    __shared__ int s[1024];
    int t = threadIdx.x;
    int v = (t < nb) ? blocksum[t] : 0;
    s[t] = v;
    __syncthreads();
    for (int off = 1; off < 1024; off <<= 1) {
        int u = (t >= off) ? s[t - off] : 0;
        __syncthreads();
        s[t] += u;
        __syncthreads();
    }
    if (t < nb) blockoffs[t] = s[t] - v;  // exclusive
}

__global__ void k_scan3(int* row_off, const int* __restrict__ blockoffs, int n) {
    int i = blockIdx.x * blockDim.x + threadIdx.x;
    if (i < n) row_off[i + 1] += blockoffs[i >> 8];
    if (i == 0) row_off[0] = 0;
}

__global__ void k_cursor(int* cursor, const int* __restrict__ row_off, int n) {
    int i = blockIdx.x * blockDim.x + threadIdx.x;
    if (i < n) cursor[i] = row_off[i];
}

__global__ void k_fill(const int* __restrict__ src, const int* __restrict__ dst,
                       const float* __restrict__ dinv, int* cursor,
                       int* __restrict__ esrc, float* __restrict__ enorm, int E) {
    int e = blockIdx.x * blockDim.x + threadIdx.x;
    if (e < E) {
        int s = src[e], d = dst[e];
        int pos = atomicAdd(&cursor[d], 1);
        esrc[pos] = s;
        enorm[pos] = dinv[s] * dinv[d];
    }
}

// --- dense h = x @ W^T ; W is [64][K] row-major, staged in LDS ------------
template <int K>
__global__ __launch_bounds__(256) void k_gemm(const float* __restrict__ x,
                                              const float* __restrict__ W,
                                              float* __restrict__ h, int n) {
    __shared__ float wlds[64 * (K + 1)];  // stride K+1: 2-way bank alias = free
    for (int idx = threadIdx.x; idx < 64 * K; idx += 256) {
        int o = idx / K, k = idx % K;
        wlds[o * (K + 1) + k] = W[idx];
    }
    __syncthreads();
    const int w = threadIdx.x >> 6, lane = threadIdx.x & 63;
    const int row0 = blockIdx.x * 16 + w * 4;  // 4 rows per wave
    const float* wrow = &wlds[lane * (K + 1)];

    int r0 = min(row0 + 0, n - 1), r1 = min(row0 + 1, n - 1);
    int r2 = min(row0 + 2, n - 1), r3 = min(row0 + 3, n - 1);
    const float* xr0 = x + (size_t)r0 * K;
    const float* xr1 = x + (size_t)r1 * K;
    const float* xr2 = x + (size_t)r2 * K;
    const float* xr3 = x + (size_t)r3 * K;

    float acc0 = 0.f, acc1 = 0.f, acc2 = 0.f, acc3 = 0.f;
#pragma unroll
    for (int k = 0; k < K; k += 4) {
        float4 a0 = *reinterpret_cast<const float4*>(xr0 + k);
        float4 a1 = *reinterpret_cast<const float4*>(xr1 + k);
        float4 a2 = *reinterpret_cast<const float4*>(xr2 + k);
        float4 a3 = *reinterpret_cast<const float4*>(xr3 + k);
        float w0 = wrow[k + 0], w1 = wrow[k + 1], w2 = wrow[k + 2], w3 = wrow[k + 3];
        acc0 = fmaf(a0.x, w0, acc0); acc0 = fmaf(a0.y, w1, acc0);
        acc0 = fmaf(a0.z, w2, acc0); acc0 = fmaf(a0.w, w3, acc0);
        acc1 = fmaf(a1.x, w0, acc1); acc1 = fmaf(a1.y, w1, acc1);
        acc1 = fmaf(a1.z, w2, acc1); acc1 = fmaf(a1.w, w3, acc1);
        acc2 = fmaf(a2.x, w0, acc2); acc2 = fmaf(a2.y, w1, acc2);
        acc2 = fmaf(a2.z, w2, acc2); acc2 = fmaf(a2.w, w3, acc2);
        acc3 = fmaf(a3.x, w0, acc3); acc3 = fmaf(a3.y, w1, acc3);
        acc3 = fmaf(a3.z, w2, acc3); acc3 = fmaf(a3.w, w3, acc3);
    }
    if (row0 + 0 < n) h[(size_t)(row0 + 0) * 64 + lane] = acc0;
    if (row0 + 1 < n) h[(size_t)(row0 + 1) * 64 + lane] = acc1;
    if (row0 + 2 < n) h[(size_t)(row0 + 2) * 64 + lane] = acc2;
    if (row0 + 3 < n) h[(size_t)(row0 + 3) * 64 + lane] = acc3;
}

// --- sparse aggregation: one wave per node, lane = channel ----------------
__global__ __launch_bounds__(256) void k_agg(const float* __restrict__ h,
                                             const int* __restrict__ roff,
                                             const int* __restrict__ esrc,
                                             const float* __restrict__ enorm,
                                             const float* __restrict__ dinv,
                                             const float* __restrict__ bias,
                                             float* __restrict__ out, int n,
                                             int relu) {
    int gt = blockIdx.x * blockDim.x + threadIdx.x;
    int node = gt >> 6;
    int lane = gt & 63;
    if (node >= n) return;
    float di = dinv[node];
    float acc = di * di * h[(size_t)node * 64 + lane];  // self-loop
    int beg = roff[node], end = roff[node + 1];
    for (int k = beg; k < end; ++k) {
        int s = esrc[k];
        float nw = enorm[k];
        acc = fmaf(nw, h[(size_t)s * 64 + lane], acc);
    }
    acc += bias[lane];
    if (relu) acc = fmaxf(acc, 0.0f);
    out[(size_t)node * 64 + lane] = acc;
}

extern "C" void kernel_launch(void* const* d_in, const int* in_sizes, int n_in,
                              void* d_out, int out_size, void* d_ws, size_t ws_size,
                              hipStream_t stream) {
    const float* x  = (const float*)d_in[0];
    const int*   ei = (const int*)d_in[1];
    const float* W1 = (const float*)d_in[2];
    const float* b1 = (const float*)d_in[3];
    const float* W2 = (const float*)d_in[4];
    const float* b2 = (const float*)d_in[5];
    float* out = (float*)d_out;

    const int N = in_sizes[0] / 128;
    const int E = in_sizes[1] / 2;
    const int* src = ei;
    const int* dst = ei + E;

    char* w = (char*)d_ws;
    float* dinv  = (float*)w; w += align_up((size_t)N * 4, 256);
    int*   counts = (int*)w;  w += align_up((size_t)N * 4, 256);
    int*   roff  = (int*)w;   w += align_up(((size_t)N + 1) * 4, 256);
    int*   bsum  = (int*)w;   w += 4096;
    int*   boff  = (int*)w;   w += 4096;
    int*   esrc  = (int*)w;   w += align_up((size_t)E * 4, 256);
    float* enorm = (float*)w; w += align_up((size_t)E * 4, 256);
    float* h_a   = (float*)w; w += align_up((size_t)N * 64 * 4, 256);
    int* cursor = counts;  // counts dead after scan1 -> reuse as fill cursor

    const int nbN = (N + 255) / 256;
    const int nbE = (E + 255) / 256;
    const int nbAgg = (int)(((size_t)N * 64 + 255) / 256);
    const int nbGemm = (N + 15) / 16;

    // ---- CSR build ----
    k_init_counts<<<nbN, 256, 0, stream>>>(counts, N);
    k_hist<<<nbE, 256, 0, stream>>>(dst, counts, E);
    k_dinv<<<nbN, 256, 0, stream>>>(counts, dinv, N);
    k_scan1<<<nbN, 256, 0, stream>>>(counts, roff, bsum, N);
    k_scan2<<<1, 1024, 0, stream>>>(bsum, boff, nbN);
    k_scan3<<<nbN, 256, 0, stream>>>(roff, boff, N);
    k_cursor<<<nbN, 256, 0, stream>>>(cursor, roff, N);
    k_fill<<<nbE, 256, 0, stream>>>(src, dst, dinv, cursor, esrc, enorm, E);

    // ---- layer 1: h_a = x @ W1^T ; d_out = relu(agg(h_a) + b1) ----
    k_gemm<128><<<nbGemm, 256, 0, stream>>>(x, W1, h_a, N);
    k_agg<<<nbAgg, 256, 0, stream>>>(h_a, roff, esrc, enorm, dinv, b1, out, N, 1);

    // ---- layer 2: h_a = d_out @ W2^T ; d_out = agg(h_a) + b2 ----
    k_gemm<64><<<nbGemm, 256, 0, stream>>>(out, W2, h_a, N);
    k_agg<<<nbAgg, 256, 0, stream>>>(h_a, roff, esrc, enorm, dinv, b2, out, N, 0);
}

// Round 2
// 663.713 us; speedup vs baseline: 1.5852x; 1.5852x over previous
//
#include <hip/hip_runtime.h>

// ---------------------------------------------------------------------------
// 2-layer GCN forward on MI355X.
// CSR (by dst) built once per call, then per layer:
//   h = x @ W^T            (dense f32, W in LDS, 8 rows/wave, no-spill K loop)
//   out[i] = sum_{e: dst=e} norm_e * h[src_e] + dinv[i]^2 * h[i] + b  (+relu)
// Aggregation: one wave per node, lane == channel (64 ch == 64 lanes).
// ---------------------------------------------------------------------------

static inline size_t align_up(size_t x, size_t a) { return (x + a - 1) & ~(a - 1); }

__global__ void k_init_counts(int* counts, int n) {
    int i = blockIdx.x * blockDim.x + threadIdx.x;
    if (i < n) counts[i] = 0;
}

__global__ void k_hist(const int* __restrict__ dst, int* counts, int E) {
    int e = blockIdx.x * blockDim.x + threadIdx.x;
    if (e < E) atomicAdd(&counts[dst[e]], 1);
}

__global__ void k_dinv(const int* __restrict__ counts, float* dinv, int n) {
    int i = blockIdx.x * blockDim.x + threadIdx.x;
    if (i < n) dinv[i] = rsqrtf((float)(counts[i] + 1));  // +1 self-loop
}

// --- two-level exclusive scan of counts -> row offsets --------------------
__global__ void k_scan1(const int* __restrict__ counts, int* row_off,
                        int* blocksum, int n) {
    __shared__ int s[256];
    int i = blockIdx.x * 256 + threadIdx.x;
    int v = (i < n) ? counts[i] : 0;
    s[threadIdx.x] = v;
    __syncthreads();
    for (int off = 1; off < 256; off <<= 1) {
        int t = (threadIdx.x >= off) ? s[threadIdx.x - off] : 0;
        __syncthreads();
        s[threadIdx.x] += t;
        __syncthreads();
    }
    if (i < n) row_off[i + 1] = s[threadIdx.x];  // inclusive, block-local
    if (threadIdx.x == 255) blocksum[blockIdx.x] = s[255];
}

__global__ void k_scan2(const int* __restrict__ blocksum, int* blockoffs, int nb) {
    __shared__ int s[1024];
    int t = threadIdx.x;
    int v = (t < nb) ? blocksum[t] : 0;
    s[t] = v;
    __syncthreads();
    for (int off = 1; off < 1024; off <<= 1) {
        int u = (t >= off) ? s[t - off] : 0;
        __syncthreads();
        s[t] += u;
        __syncthreads();
    }
    if (t < nb) blockoffs[t] = s[t] - v;  // exclusive
}

__global__ void k_scan3(int* row_off, const int* __restrict__ blockoffs, int n) {
    int i = blockIdx.x * blockDim.x + threadIdx.x;
    if (i < n) row_off[i + 1] += blockoffs[i >> 8];
    if (i == 0) row_off[0] = 0;
}

__global__ void k_cursor(int* cursor, const int* __restrict__ row_off, int n) {
    int i = blockIdx.x * blockDim.x + threadIdx.x;
    if (i < n) cursor[i] = row_off[i];
}

__global__ void k_fill(const int* __restrict__ src, const int* __restrict__ dst,
                       const float* __restrict__ dinv, int* cursor,
                       int* __restrict__ esrc, float* __restrict__ enorm, int E) {
    int e = blockIdx.x * blockDim.x + threadIdx.x;
    if (e < E) {
        int s = src[e], d = dst[e];
        int pos = atomicAdd(&cursor[d], 1);
        esrc[pos] = s;
        enorm[pos] = dinv[s] * dinv[d];
    }
}

// --- dense h = x @ W^T ---------------------------------------------------
// W is [64][K] row-major, staged in LDS with stride K+4 (16B-aligned rows,
// bank window (4*lane+k)%32 = saturated conflict-free pattern for b128).
// 256 thr = 4 waves; wave handles 8 rows; lane = output channel.
// x rows read as wave-uniform float4 broadcasts (each row streamed once).
// #pragma unroll 1 keeps live set ~60 VGPR -> no scratch spill.
template <int K>
__global__ __launch_bounds__(256) void k_gemm(const float* __restrict__ x,
                                              const float* __restrict__ W,
                                              float* __restrict__ h, int n) {
    __shared__ float wlds[64 * (K + 4)];
    for (int idx = threadIdx.x * 4; idx < 64 * K; idx += 256 * 4) {
        int o = idx / K, k = idx % K;  // idx,K multiples of 4 -> k multiple of 4
        float4 v = *reinterpret_cast<const float4*>(W + idx);
        *reinterpret_cast<float4*>(&wlds[o * (K + 4) + k]) = v;
    }
    __syncthreads();
    const int wv = threadIdx.x >> 6, lane = threadIdx.x & 63;
    const int row0 = blockIdx.x * 32 + wv * 8;  // 8 rows per wave
    if (row0 >= n) return;
    const float* wrow = &wlds[lane * (K + 4)];

    const float* xr[8];
#pragma unroll
    for (int r = 0; r < 8; ++r) {
        int rr = min(row0 + r, n - 1);
        xr[r] = x + (size_t)rr * K;
    }

    float acc[8];
#pragma unroll
    for (int r = 0; r < 8; ++r) acc[r] = 0.f;

#pragma unroll 1
    for (int k = 0; k < K; k += 4) {
        float4 w4 = *reinterpret_cast<const float4*>(wrow + k);
        float4 a0 = *reinterpret_cast<const float4*>(xr[0] + k);
        float4 a1 = *reinterpret_cast<const float4*>(xr[1] + k);
        float4 a2 = *reinterpret_cast<const float4*>(xr[2] + k);
        float4 a3 = *reinterpret_cast<const float4*>(xr[3] + k);
        float4 a4 = *reinterpret_cast<const float4*>(xr[4] + k);
        float4 a5 = *reinterpret_cast<const float4*>(xr[5] + k);
        float4 a6 = *reinterpret_cast<const float4*>(xr[6] + k);
        float4 a7 = *reinterpret_cast<const float4*>(xr[7] + k);
        acc[0] = fmaf(a0.x, w4.x, acc[0]); acc[0] = fmaf(a0.y, w4.y, acc[0]);
        acc[0] = fmaf(a0.z, w4.z, acc[0]); acc[0] = fmaf(a0.w, w4.w, acc[0]);
        acc[1] = fmaf(a1.x, w4.x, acc[1]); acc[1] = fmaf(a1.y, w4.y, acc[1]);
        acc[1] = fmaf(a1.z, w4.z, acc[1]); acc[1] = fmaf(a1.w, w4.w, acc[1]);
        acc[2] = fmaf(a2.x, w4.x, acc[2]); acc[2] = fmaf(a2.y, w4.y, acc[2]);
        acc[2] = fmaf(a2.z, w4.z, acc[2]); acc[2] = fmaf(a2.w, w4.w, acc[2]);
        acc[3] = fmaf(a3.x, w4.x, acc[3]); acc[3] = fmaf(a3.y, w4.y, acc[3]);
        acc[3] = fmaf(a3.z, w4.z, acc[3]); acc[3] = fmaf(a3.w, w4.w, acc[3]);
        acc[4] = fmaf(a4.x, w4.x, acc[4]); acc[4] = fmaf(a4.y, w4.y, acc[4]);
        acc[4] = fmaf(a4.z, w4.z, acc[4]); acc[4] = fmaf(a4.w, w4.w, acc[4]);
        acc[5] = fmaf(a5.x, w4.x, acc[5]); acc[5] = fmaf(a5.y, w4.y, acc[5]);
        acc[5] = fmaf(a5.z, w4.z, acc[5]); acc[5] = fmaf(a5.w, w4.w, acc[5]);
        acc[6] = fmaf(a6.x, w4.x, acc[6]); acc[6] = fmaf(a6.y, w4.y, acc[6]);
        acc[6] = fmaf(a6.z, w4.z, acc[6]); acc[6] = fmaf(a6.w, w4.w, acc[6]);
        acc[7] = fmaf(a7.x, w4.x, acc[7]); acc[7] = fmaf(a7.y, w4.y, acc[7]);
        acc[7] = fmaf(a7.z, w4.z, acc[7]); acc[7] = fmaf(a7.w, w4.w, acc[7]);
    }
#pragma unroll
    for (int r = 0; r < 8; ++r) {
        if (row0 + r < n) h[(size_t)(row0 + r) * 64 + lane] = acc[r];
    }
}

// --- sparse aggregation: one wave per node, lane = channel ----------------
__global__ __launch_bounds__(256) void k_agg(const float* __restrict__ h,
                                             const int* __restrict__ roff,
                                             const int* __restrict__ esrc,
                                             const float* __restrict__ enorm,
                                             const float* __restrict__ dinv,
                                             const float* __restrict__ bias,
                                             float* __restrict__ out, int n,
                                             int relu) {
    int gt = blockIdx.x * blockDim.x + threadIdx.x;
    int node = gt >> 6;
    int lane = gt & 63;
    if (node >= n) return;
    float di = dinv[node];
    float acc = di * di * h[(size_t)node * 64 + lane];  // self-loop
    int beg = roff[node], end = roff[node + 1];
    for (int k = beg; k < end; ++k) {
        int s = esrc[k];
        float nw = enorm[k];
        acc = fmaf(nw, h[(size_t)s * 64 + lane], acc);
    }
    acc += bias[lane];
    if (relu) acc = fmaxf(acc, 0.0f);
    out[(size_t)node * 64 + lane] = acc;
}

extern "C" void kernel_launch(void* const* d_in, const int* in_sizes, int n_in,
                              void* d_out, int out_size, void* d_ws, size_t ws_size,
                              hipStream_t stream) {
    const float* x  = (const float*)d_in[0];
    const int*   ei = (const int*)d_in[1];
    const float* W1 = (const float*)d_in[2];
    const float* b1 = (const float*)d_in[3];
    const float* W2 = (const float*)d_in[4];
    const float* b2 = (const float*)d_in[5];
    float* out = (float*)d_out;

    const int N = in_sizes[0] / 128;
    const int E = in_sizes[1] / 2;
    const int* src = ei;
    const int* dst = ei + E;

    char* w = (char*)d_ws;
    float* dinv  = (float*)w; w += align_up((size_t)N * 4, 256);
    int*   counts = (int*)w;  w += align_up((size_t)N * 4, 256);
    int*   roff  = (int*)w;   w += align_up(((size_t)N + 1) * 4, 256);
    int*   bsum  = (int*)w;   w += 4096;
    int*   boff  = (int*)w;   w += 4096;
    int*   esrc  = (int*)w;   w += align_up((size_t)E * 4, 256);
    float* enorm = (float*)w; w += align_up((size_t)E * 4, 256);
    float* h_a   = (float*)w; w += align_up((size_t)N * 64 * 4, 256);
    int* cursor = counts;  // counts dead after scan1 -> reuse as fill cursor

    const int nbN = (N + 255) / 256;
    const int nbE = (E + 255) / 256;
    const int nbAgg = (int)(((size_t)N * 64 + 255) / 256);
    const int nbGemm = (N + 31) / 32;

    // ---- CSR build ----
    k_init_counts<<<nbN, 256, 0, stream>>>(counts, N);
    k_hist<<<nbE, 256, 0, stream>>>(dst, counts, E);
    k_dinv<<<nbN, 256, 0, stream>>>(counts, dinv, N);
    k_scan1<<<nbN, 256, 0, stream>>>(counts, roff, bsum, N);
    k_scan2<<<1, 1024, 0, stream>>>(bsum, boff, nbN);
    k_scan3<<<nbN, 256, 0, stream>>>(roff, boff, N);
    k_cursor<<<nbN, 256, 0, stream>>>(cursor, roff, N);
    k_fill<<<nbE, 256, 0, stream>>>(src, dst, dinv, cursor, esrc, enorm, E);

    // ---- layer 1: h_a = x @ W1^T ; d_out = relu(agg(h_a) + b1) ----
    k_gemm<128><<<nbGemm, 256, 0, stream>>>(x, W1, h_a, N);
    k_agg<<<nbAgg, 256, 0, stream>>>(h_a, roff, esrc, enorm, dinv, b1, out, N, 1);

    // ---- layer 2: h_a = d_out @ W2^T ; d_out = agg(h_a) + b2 ----
    k_gemm<64><<<nbGemm, 256, 0, stream>>>(out, W2, h_a, N);
    k_agg<<<nbAgg, 256, 0, stream>>>(h_a, roff, esrc, enorm, dinv, b2, out, N, 0);
}

// Round 3
// 508.184 us; speedup vs baseline: 2.0703x; 1.3060x over previous
//
#include <hip/hip_runtime.h>

// ---------------------------------------------------------------------------
// 2-layer GCN forward on MI355X.
// CSR (by dst, rows padded to multiple of 4) built once per call, then:
//   h = x @ W^T                 (dense f32, W in LDS, 8 rows/wave, no spill)
//   out[i] = dinv[i]*sum_e dinv[src_e]*h[src_e] + dinv[i]^2*h[i] + b (+relu)
// Aggregation: one wave per node, lane == channel, 4 gathers in flight.
// ---------------------------------------------------------------------------

static inline size_t align_up(size_t x, size_t a) { return (x + a - 1) & ~(a - 1); }

__global__ void k_hist(const int* __restrict__ dst, int* counts, int E) {
    int e = blockIdx.x * blockDim.x + threadIdx.x;
    if (e < E) atomicAdd(&counts[dst[e]], 1);
}

__global__ void k_dinv(const int* __restrict__ counts, float* dinv, int n) {
    int i = blockIdx.x * blockDim.x + threadIdx.x;
    if (i < n) dinv[i] = rsqrtf((float)(counts[i] + 1));  // +1 self-loop
}

// --- two-level exclusive scan of PADDED counts -> row offsets -------------
__global__ void k_scan1(const int* __restrict__ counts, int* row_off,
                        int* blocksum, int n) {
    __shared__ int s[256];
    int i = blockIdx.x * 256 + threadIdx.x;
    int v = (i < n) ? ((counts[i] + 3) & ~3) : 0;   // pad rows to x4
    s[threadIdx.x] = v;
    __syncthreads();
    for (int off = 1; off < 256; off <<= 1) {
        int t = (threadIdx.x >= off) ? s[threadIdx.x - off] : 0;
        __syncthreads();
        s[threadIdx.x] += t;
        __syncthreads();
    }
    if (i < n) row_off[i + 1] = s[threadIdx.x];  // inclusive, block-local
    if (threadIdx.x == 255) blocksum[blockIdx.x] = s[255];
}

__global__ void k_scan2(const int* __restrict__ blocksum, int* blockoffs, int nb) {
    __shared__ int s[1024];
    int t = threadIdx.x;
    int v = (t < nb) ? blocksum[t] : 0;
    s[t] = v;
    __syncthreads();
    for (int off = 1; off < 1024; off <<= 1) {
        int u = (t >= off) ? s[t - off] : 0;
        __syncthreads();
        s[t] += u;
        __syncthreads();
    }
    if (t < nb) blockoffs[t] = s[t] - v;  // exclusive
}

__global__ void k_scan3(int* row_off, const int* __restrict__ blockoffs, int n) {
    int i = blockIdx.x * blockDim.x + threadIdx.x;
    if (i < n) row_off[i + 1] += blockoffs[i >> 8];
    if (i == 0) row_off[0] = 0;
}

__global__ void k_cursor(int* cursor, const int* __restrict__ row_off, int n) {
    int i = blockIdx.x * blockDim.x + threadIdx.x;
    if (i < n) cursor[i] = row_off[i];
}

__global__ void k_fill(const int* __restrict__ src, const int* __restrict__ dst,
                       const float* __restrict__ dinv, int* cursor,
                       int* __restrict__ esrc, float* __restrict__ enorm, int E) {
    int e = blockIdx.x * blockDim.x + threadIdx.x;
    if (e < E) {
        int s = src[e], d = dst[e];
        int pos = atomicAdd(&cursor[d], 1);
        esrc[pos] = s;
        enorm[pos] = dinv[s];  // dinv[d] factored into k_agg epilogue
    }
}

// --- dense h = x @ W^T ---------------------------------------------------
// W is [64][K] row-major, staged in LDS with stride K+4 (16B-aligned rows).
// 256 thr = 4 waves; wave handles 8 rows; lane = output channel.
// #pragma unroll 1 keeps live set ~60 VGPR -> no scratch spill.
template <int K>
__global__ __launch_bounds__(256) void k_gemm(const float* __restrict__ x,
                                              const float* __restrict__ W,
                                              float* __restrict__ h, int n) {
    __shared__ float wlds[64 * (K + 4)];
    for (int idx = threadIdx.x * 4; idx < 64 * K; idx += 256 * 4) {
        int o = idx / K, k = idx % K;
        float4 v = *reinterpret_cast<const float4*>(W + idx);
        *reinterpret_cast<float4*>(&wlds[o * (K + 4) + k]) = v;
    }
    __syncthreads();
    const int wv = threadIdx.x >> 6, lane = threadIdx.x & 63;
    const int row0 = blockIdx.x * 32 + wv * 8;  // 8 rows per wave
    if (row0 >= n) return;
    const float* wrow = &wlds[lane * (K + 4)];

    const float* xr[8];
#pragma unroll
    for (int r = 0; r < 8; ++r) {
        int rr = min(row0 + r, n - 1);
        xr[r] = x + (size_t)rr * K;
    }

    float acc[8];
#pragma unroll
    for (int r = 0; r < 8; ++r) acc[r] = 0.f;

#pragma unroll 1
    for (int k = 0; k < K; k += 4) {
        float4 w4 = *reinterpret_cast<const float4*>(wrow + k);
        float4 a0 = *reinterpret_cast<const float4*>(xr[0] + k);
        float4 a1 = *reinterpret_cast<const float4*>(xr[1] + k);
        float4 a2 = *reinterpret_cast<const float4*>(xr[2] + k);
        float4 a3 = *reinterpret_cast<const float4*>(xr[3] + k);
        float4 a4 = *reinterpret_cast<const float4*>(xr[4] + k);
        float4 a5 = *reinterpret_cast<const float4*>(xr[5] + k);
        float4 a6 = *reinterpret_cast<const float4*>(xr[6] + k);
        float4 a7 = *reinterpret_cast<const float4*>(xr[7] + k);
        acc[0] = fmaf(a0.x, w4.x, acc[0]); acc[0] = fmaf(a0.y, w4.y, acc[0]);
        acc[0] = fmaf(a0.z, w4.z, acc[0]); acc[0] = fmaf(a0.w, w4.w, acc[0]);
        acc[1] = fmaf(a1.x, w4.x, acc[1]); acc[1] = fmaf(a1.y, w4.y, acc[1]);
        acc[1] = fmaf(a1.z, w4.z, acc[1]); acc[1] = fmaf(a1.w, w4.w, acc[1]);
        acc[2] = fmaf(a2.x, w4.x, acc[2]); acc[2] = fmaf(a2.y, w4.y, acc[2]);
        acc[2] = fmaf(a2.z, w4.z, acc[2]); acc[2] = fmaf(a2.w, w4.w, acc[2]);
        acc[3] = fmaf(a3.x, w4.x, acc[3]); acc[3] = fmaf(a3.y, w4.y, acc[3]);
        acc[3] = fmaf(a3.z, w4.z, acc[3]); acc[3] = fmaf(a3.w, w4.w, acc[3]);
        acc[4] = fmaf(a4.x, w4.x, acc[4]); acc[4] = fmaf(a4.y, w4.y, acc[4]);
        acc[4] = fmaf(a4.z, w4.z, acc[4]); acc[4] = fmaf(a4.w, w4.w, acc[4]);
        acc[5] = fmaf(a5.x, w4.x, acc[5]); acc[5] = fmaf(a5.y, w4.y, acc[5]);
        acc[5] = fmaf(a5.z, w4.z, acc[5]); acc[5] = fmaf(a5.w, w4.w, acc[5]);
        acc[6] = fmaf(a6.x, w4.x, acc[6]); acc[6] = fmaf(a6.y, w4.y, acc[6]);
        acc[6] = fmaf(a6.z, w4.z, acc[6]); acc[6] = fmaf(a6.w, w4.w, acc[6]);
        acc[7] = fmaf(a7.x, w4.x, acc[7]); acc[7] = fmaf(a7.y, w4.y, acc[7]);
        acc[7] = fmaf(a7.z, w4.z, acc[7]); acc[7] = fmaf(a7.w, w4.w, acc[7]);
    }
#pragma unroll
    for (int r = 0; r < 8; ++r) {
        if (row0 + r < n) h[(size_t)(row0 + r) * 64 + lane] = acc[r];
    }
}

// --- sparse aggregation: one wave/node, lane = channel, 4-edge ILP --------
__global__ __launch_bounds__(256) void k_agg(const float* __restrict__ h,
                                             const int* __restrict__ roff,
                                             const int* __restrict__ esrc,
                                             const float* __restrict__ enorm,
                                             const float* __restrict__ dinv,
                                             const float* __restrict__ bias,
                                             float* __restrict__ out, int n,
                                             int relu) {
    int gt = blockIdx.x * blockDim.x + threadIdx.x;
    int node = gt >> 6;
    int lane = gt & 63;
    if (node >= n) return;
    float di = dinv[node];
    int beg = roff[node], end = roff[node + 1];  // both multiples of 4
    float a0 = 0.f, a1 = 0.f, a2 = 0.f, a3 = 0.f;
    for (int k = beg; k < end; k += 4) {
        int4   s4 = *reinterpret_cast<const int4*>(esrc + k);    // 16B-aligned
        float4 w4 = *reinterpret_cast<const float4*>(enorm + k); // 16B-aligned
        float h0 = h[(size_t)s4.x * 64 + lane];
        float h1 = h[(size_t)s4.y * 64 + lane];
        float h2 = h[(size_t)s4.z * 64 + lane];
        float h3 = h[(size_t)s4.w * 64 + lane];
        a0 = fmaf(w4.x, h0, a0);
        a1 = fmaf(w4.y, h1, a1);
        a2 = fmaf(w4.z, h2, a2);
        a3 = fmaf(w4.w, h3, a3);
    }
    float acc = ((a0 + a1) + (a2 + a3)) * di;
    acc = fmaf(di * di, h[(size_t)node * 64 + lane], acc);  // self-loop
    acc += bias[lane];
    if (relu) acc = fmaxf(acc, 0.0f);
    out[(size_t)node * 64 + lane] = acc;
}

extern "C" void kernel_launch(void* const* d_in, const int* in_sizes, int n_in,
                              void* d_out, int out_size, void* d_ws, size_t ws_size,
                              hipStream_t stream) {
    const float* x  = (const float*)d_in[0];
    const int*   ei = (const int*)d_in[1];
    const float* W1 = (const float*)d_in[2];
    const float* b1 = (const float*)d_in[3];
    const float* W2 = (const float*)d_in[4];
    const float* b2 = (const float*)d_in[5];
    float* out = (float*)d_out;

    const int N = in_sizes[0] / 128;
    const int E = in_sizes[1] / 2;
    const int* src = ei;
    const int* dst = ei + E;
    const size_t Ecap = (size_t)E + 4 * (size_t)N;  // padded-CSR capacity

    char* w = (char*)d_ws;
    float* dinv  = (float*)w; w += align_up((size_t)N * 4, 256);
    int*   counts = (int*)w;  w += align_up((size_t)N * 4, 256);
    int*   roff  = (int*)w;   w += align_up(((size_t)N + 1) * 4, 256);
    int*   bsum  = (int*)w;   w += 4096;
    int*   boff  = (int*)w;   w += 4096;
    int*   esrc  = (int*)w;   w += align_up(Ecap * 4, 256);
    float* enorm = (float*)w; w += align_up(Ecap * 4, 256);
    float* h_a   = (float*)w; w += align_up((size_t)N * 64 * 4, 256);
    int* cursor = counts;  // counts dead after scan1 -> reuse as fill cursor

    const int nbN = (N + 255) / 256;
    const int nbE = (E + 255) / 256;
    const int nbAgg = (int)(((size_t)N * 64 + 255) / 256);
    const int nbGemm = (N + 31) / 32;

    // ---- CSR build (rows padded to x4; pad slots zeroed) ----
    hipMemsetAsync(counts, 0, (size_t)N * 4, stream);
    hipMemsetAsync(esrc, 0, Ecap * 4, stream);
    hipMemsetAsync(enorm, 0, Ecap * 4, stream);
    k_hist<<<nbE, 256, 0, stream>>>(dst, counts, E);
    k_dinv<<<nbN, 256, 0, stream>>>(counts, dinv, N);
    k_scan1<<<nbN, 256, 0, stream>>>(counts, roff, bsum, N);
    k_scan2<<<1, 1024, 0, stream>>>(bsum, boff, nbN);
    k_scan3<<<nbN, 256, 0, stream>>>(roff, boff, N);
    k_cursor<<<nbN, 256, 0, stream>>>(cursor, roff, N);
    k_fill<<<nbE, 256, 0, stream>>>(src, dst, dinv, cursor, esrc, enorm, E);

    // ---- layer 1: h_a = x @ W1^T ; d_out = relu(agg(h_a) + b1) ----
    k_gemm<128><<<nbGemm, 256, 0, stream>>>(x, W1, h_a, N);
    k_agg<<<nbAgg, 256, 0, stream>>>(h_a, roff, esrc, enorm, dinv, b1, out, N, 1);

    // ---- layer 2: h_a = d_out @ W2^T ; d_out = agg(h_a) + b2 ----
    k_gemm<64><<<nbGemm, 256, 0, stream>>>(out, W2, h_a, N);
    k_agg<<<nbAgg, 256, 0, stream>>>(h_a, roff, esrc, enorm, dinv, b2, out, N, 0);
}

// Round 5
// 459.561 us; speedup vs baseline: 2.2894x; 1.1058x over previous
//
#include <hip/hip_runtime.h>

// ---------------------------------------------------------------------------
// 2-layer GCN forward on MI355X.
// CSR (by dst, rows padded to multiple of 8, packed {src,weight} int2 entries)
// built once per call, then per layer:
//   h = x @ W^T                 (dense f32, W in LDS, 8 rows/wave, no spill)
//   out[i] = dinv[i]*sum_e dinv[src_e]*h[src_e] + dinv[i]^2*h[i] + b (+relu)
// Aggregation: one wave per node, lane == channel, 8 gathers in flight.
// ---------------------------------------------------------------------------

static inline size_t align_up(size_t x, size_t a) { return (x + a - 1) & ~(a - 1); }

__global__ void k_hist(const int* __restrict__ dst, int* counts, int E) {
    int e = blockIdx.x * blockDim.x + threadIdx.x;
    if (e < E) atomicAdd(&counts[dst[e]], 1);
}

__global__ void k_dinv(const int* __restrict__ counts, float* dinv, int n) {
    int i = blockIdx.x * blockDim.x + threadIdx.x;
    if (i < n) dinv[i] = rsqrtf((float)(counts[i] + 1));  // +1 self-loop
}

// --- two-level exclusive scan of PADDED counts -> row offsets -------------
__global__ void k_scan1(const int* __restrict__ counts, int* row_off,
                        int* blocksum, int n) {
    __shared__ int s[256];
    int i = blockIdx.x * 256 + threadIdx.x;
    int v = (i < n) ? ((counts[i] + 7) & ~7) : 0;   // pad rows to x8
    s[threadIdx.x] = v;
    __syncthreads();
    for (int off = 1; off < 256; off <<= 1) {
        int t = (threadIdx.x >= off) ? s[threadIdx.x - off] : 0;
        __syncthreads();
        s[threadIdx.x] += t;
        __syncthreads();
    }
    if (i < n) row_off[i + 1] = s[threadIdx.x];  // inclusive, block-local
    if (threadIdx.x == 255) blocksum[blockIdx.x] = s[255];
}

__global__ void k_scan2(const int* __restrict__ blocksum, int* blockoffs, int nb) {
    __shared__ int s[1024];
    int t = threadIdx.x;
    int v = (t < nb) ? blocksum[t] : 0;
    s[t] = v;
    __syncthreads();
    for (int off = 1; off < 1024; off <<= 1) {
        int u = (t >= off) ? s[t - off] : 0;
        __syncthreads();
        s[t] += u;
        __syncthreads();
    }
    if (t < nb) blockoffs[t] = s[t] - v;  // exclusive
}

__global__ void k_scan3(int* row_off, const int* __restrict__ blockoffs, int n) {
    int i = blockIdx.x * blockDim.x + threadIdx.x;
    if (i < n) row_off[i + 1] += blockoffs[i >> 8];
    if (i == 0) row_off[0] = 0;
}

__global__ void k_cursor(int* cursor, const int* __restrict__ row_off, int n) {
    int i = blockIdx.x * blockDim.x + threadIdx.x;
    if (i < n) cursor[i] = row_off[i];
}

// fill: one packed 8B scattered store per edge (src, dinv[src])
__global__ void k_fill(const int* __restrict__ src, const int* __restrict__ dst,
                       const float* __restrict__ dinv, int* cursor,
                       int2* __restrict__ epack, int E) {
    int e = blockIdx.x * blockDim.x + threadIdx.x;
    if (e < E) {
        int s = src[e], d = dst[e];
        int pos = atomicAdd(&cursor[d], 1);
        epack[pos] = make_int2(s, __float_as_int(dinv[s]));
    }
}

// write {0, 0.0f} into the pad slots [cursor[i], roff[i+1]) of each row
__global__ void k_padfill(const int* __restrict__ cursor,
                          const int* __restrict__ roff,
                          int2* __restrict__ epack, int n) {
    int i = blockIdx.x * blockDim.x + threadIdx.x;
    if (i < n) {
        int e = roff[i + 1];
        for (int k = cursor[i]; k < e; ++k) epack[k] = make_int2(0, 0);
    }
}

// --- dense h = x @ W^T ---------------------------------------------------
// W is [64][K] row-major, staged in LDS with stride K+4 (16B-aligned rows).
// 256 thr = 4 waves; wave handles 8 rows; lane = output channel.
// #pragma unroll 1 keeps live set ~60 VGPR -> no scratch spill.
template <int K>
__global__ __launch_bounds__(256) void k_gemm(const float* __restrict__ x,
                                              const float* __restrict__ W,
                                              float* __restrict__ h, int n) {
    __shared__ float wlds[64 * (K + 4)];
    for (int idx = threadIdx.x * 4; idx < 64 * K; idx += 256 * 4) {
        int o = idx / K, k = idx % K;
        float4 v = *reinterpret_cast<const float4*>(W + idx);
        *reinterpret_cast<float4*>(&wlds[o * (K + 4) + k]) = v;
    }
    __syncthreads();
    const int wv = threadIdx.x >> 6, lane = threadIdx.x & 63;
    const int row0 = blockIdx.x * 32 + wv * 8;  // 8 rows per wave
    if (row0 >= n) return;
    const float* wrow = &wlds[lane * (K + 4)];

    const float* xr[8];
#pragma unroll
    for (int r = 0; r < 8; ++r) {
        int rr = min(row0 + r, n - 1);
        xr[r] = x + (size_t)rr * K;
    }

    float acc[8];
#pragma unroll
    for (int r = 0; r < 8; ++r) acc[r] = 0.f;

#pragma unroll 1
    for (int k = 0; k < K; k += 4) {
        float4 w4 = *reinterpret_cast<const float4*>(wrow + k);
        float4 a0 = *reinterpret_cast<const float4*>(xr[0] + k);
        float4 a1 = *reinterpret_cast<const float4*>(xr[1] + k);
        float4 a2 = *reinterpret_cast<const float4*>(xr[2] + k);
        float4 a3 = *reinterpret_cast<const float4*>(xr[3] + k);
        float4 a4 = *reinterpret_cast<const float4*>(xr[4] + k);
        float4 a5 = *reinterpret_cast<const float4*>(xr[5] + k);
        float4 a6 = *reinterpret_cast<const float4*>(xr[6] + k);
        float4 a7 = *reinterpret_cast<const float4*>(xr[7] + k);
        acc[0] = fmaf(a0.x, w4.x, acc[0]); acc[0] = fmaf(a0.y, w4.y, acc[0]);
        acc[0] = fmaf(a0.z, w4.z, acc[0]); acc[0] = fmaf(a0.w, w4.w, acc[0]);
        acc[1] = fmaf(a1.x, w4.x, acc[1]); acc[1] = fmaf(a1.y, w4.y, acc[1]);
        acc[1] = fmaf(a1.z, w4.z, acc[1]); acc[1] = fmaf(a1.w, w4.w, acc[1]);
        acc[2] = fmaf(a2.x, w4.x, acc[2]); acc[2] = fmaf(a2.y, w4.y, acc[2]);
        acc[2] = fmaf(a2.z, w4.z, acc[2]); acc[2] = fmaf(a2.w, w4.w, acc[2]);
        acc[3] = fmaf(a3.x, w4.x, acc[3]); acc[3] = fmaf(a3.y, w4.y, acc[3]);
        acc[3] = fmaf(a3.z, w4.z, acc[3]); acc[3] = fmaf(a3.w, w4.w, acc[3]);
        acc[4] = fmaf(a4.x, w4.x, acc[4]); acc[4] = fmaf(a4.y, w4.y, acc[4]);
        acc[4] = fmaf(a4.z, w4.z, acc[4]); acc[4] = fmaf(a4.w, w4.w, acc[4]);
        acc[5] = fmaf(a5.x, w4.x, acc[5]); acc[5] = fmaf(a5.y, w4.y, acc[5]);
        acc[5] = fmaf(a5.z, w4.z, acc[5]); acc[5] = fmaf(a5.w, w4.w, acc[5]);
        acc[6] = fmaf(a6.x, w4.x, acc[6]); acc[6] = fmaf(a6.y, w4.y, acc[6]);
        acc[6] = fmaf(a6.z, w4.z, acc[6]); acc[6] = fmaf(a6.w, w4.w, acc[6]);
        acc[7] = fmaf(a7.x, w4.x, acc[7]); acc[7] = fmaf(a7.y, w4.y, acc[7]);
        acc[7] = fmaf(a7.z, w4.z, acc[7]); acc[7] = fmaf(a7.w, w4.w, acc[7]);
    }
#pragma unroll
    for (int r = 0; r < 8; ++r) {
        if (row0 + r < n) h[(size_t)(row0 + r) * 64 + lane] = acc[r];
    }
}

// --- sparse aggregation: one wave/node, lane = channel, 8-edge ILP --------
__global__ __launch_bounds__(256) void k_agg(const float* __restrict__ h,
                                             const int* __restrict__ roff,
                                             const int2* __restrict__ epack,
                                             const float* __restrict__ dinv,
                                             const float* __restrict__ bias,
                                             float* __restrict__ out, int n,
                                             int relu) {
    int gt = blockIdx.x * blockDim.x + threadIdx.x;
    int node = gt >> 6;
    int lane = gt & 63;
    if (node >= n) return;
    float di = dinv[node];
    float hself = h[(size_t)node * 64 + lane];
    float b = bias[lane];
    int beg = roff[node], end = roff[node + 1];  // both multiples of 8
    float a0 = 0.f, a1 = 0.f, a2 = 0.f, a3 = 0.f;
    float a4 = 0.f, a5 = 0.f, a6 = 0.f, a7 = 0.f;
    for (int k = beg; k < end; k += 8) {
        const int4* p = reinterpret_cast<const int4*>(epack + k);  // 64B aligned
        int4 q0 = p[0], q1 = p[1], q2 = p[2], q3 = p[3];
        float h0 = h[(size_t)q0.x * 64 + lane];
        float h1 = h[(size_t)q0.z * 64 + lane];
        float h2 = h[(size_t)q1.x * 64 + lane];
        float h3 = h[(size_t)q1.z * 64 + lane];
        float h4 = h[(size_t)q2.x * 64 + lane];
        float h5 = h[(size_t)q2.z * 64 + lane];
        float h6 = h[(size_t)q3.x * 64 + lane];
        float h7 = h[(size_t)q3.z * 64 + lane];
        a0 = fmaf(__int_as_float(q0.y), h0, a0);
        a1 = fmaf(__int_as_float(q0.w), h1, a1);
        a2 = fmaf(__int_as_float(q1.y), h2, a2);
        a3 = fmaf(__int_as_float(q1.w), h3, a3);
        a4 = fmaf(__int_as_float(q2.y), h4, a4);
        a5 = fmaf(__int_as_float(q2.w), h5, a5);
        a6 = fmaf(__int_as_float(q3.y), h6, a6);
        a7 = fmaf(__int_as_float(q3.w), h7, a7);
    }
    float acc = (((a0 + a1) + (a2 + a3)) + ((a4 + a5) + (a6 + a7))) * di;
    acc = fmaf(di * di, hself, acc);  // self-loop
    acc += b;
    if (relu) acc = fmaxf(acc, 0.0f);
    out[(size_t)node * 64 + lane] = acc;
}

extern "C" void kernel_launch(void* const* d_in, const int* in_sizes, int n_in,
                              void* d_out, int out_size, void* d_ws, size_t ws_size,
                              hipStream_t stream) {
    const float* x  = (const float*)d_in[0];
    const int*   ei = (const int*)d_in[1];
    const float* W1 = (const float*)d_in[2];
    const float* b1 = (const float*)d_in[3];
    const float* W2 = (const float*)d_in[4];
    const float* b2 = (const float*)d_in[5];
    float* out = (float*)d_out;

    const int N = in_sizes[0] / 128;
    const int E = in_sizes[1] / 2;
    const int* src = ei;
    const int* dst = ei + E;
    const size_t Ecap = (size_t)E + 8 * (size_t)N;  // padded-CSR capacity

    char* w = (char*)d_ws;
    float* dinv  = (float*)w; w += align_up((size_t)N * 4, 256);
    int*   counts = (int*)w;  w += align_up((size_t)N * 4, 256);
    int*   roff  = (int*)w;   w += align_up(((size_t)N + 1) * 4, 256);
    int*   bsum  = (int*)w;   w += 4096;
    int*   boff  = (int*)w;   w += 4096;
    int2*  epack = (int2*)w;  w += align_up(Ecap * 8, 256);
    float* h_a   = (float*)w; w += align_up((size_t)N * 64 * 4, 256);
    int* cursor = counts;  // counts dead after scan1 -> reuse as fill cursor

    const int nbN = (N + 255) / 256;
    const int nbE = (E + 255) / 256;
    const int nbAgg = (int)(((size_t)N * 64 + 255) / 256);
    const int nbGemm = (N + 31) / 32;

    // ---- CSR build (rows padded to x8; pads written by k_padfill) ----
    hipMemsetAsync(counts, 0, (size_t)N * 4, stream);
    k_hist<<<nbE, 256, 0, stream>>>(dst, counts, E);
    k_dinv<<<nbN, 256, 0, stream>>>(counts, dinv, N);
    k_scan1<<<nbN, 256, 0, stream>>>(counts, roff, bsum, N);
    k_scan2<<<1, 1024, 0, stream>>>(bsum, boff, nbN);
    k_scan3<<<nbN, 256, 0, stream>>>(roff, boff, N);
    k_cursor<<<nbN, 256, 0, stream>>>(cursor, roff, N);
    k_fill<<<nbE, 256, 0, stream>>>(src, dst, dinv, cursor, epack, E);
    k_padfill<<<nbN, 256, 0, stream>>>(cursor, roff, epack, N);

    // ---- layer 1: h_a = x @ W1^T ; d_out = relu(agg(h_a) + b1) ----
    k_gemm<128><<<nbGemm, 256, 0, stream>>>(x, W1, h_a, N);
    k_agg<<<nbAgg, 256, 0, stream>>>(h_a, roff, epack, dinv, b1, out, N, 1);

    // ---- layer 2: h_a = d_out @ W2^T ; d_out = agg(h_a) + b2 ----
    k_gemm<64><<<nbGemm, 256, 0, stream>>>(out, W2, h_a, N);
    k_agg<<<nbAgg, 256, 0, stream>>>(h_a, roff, epack, dinv, b2, out, N, 0);
}

// Round 6
// 377.644 us; speedup vs baseline: 2.7860x; 1.2169x over previous
//
#include <hip/hip_runtime.h>

// ---------------------------------------------------------------------------
// 2-layer GCN forward on MI355X.
// CSR (by dst, rows padded to x8, packed {src,weight} int2 entries) built per
// call with XCD-bucketed scatter, then per layer:
//   h = x @ W^T          (dense f32: x-tile + W staged in LDS, 16 rows/wave)
//   out[i] = dinv[i]*sum_e dinv[src_e]*h[src_e] + dinv[i]^2*h[i] + b (+relu)
// Aggregation: one wave per node, lane == channel, 8 gathers in flight.
// ---------------------------------------------------------------------------

static inline size_t align_up(size_t x, size_t a) { return (x + a - 1) & ~(a - 1); }

__global__ void k_hist(const int* __restrict__ dst, int* counts, int E) {
    int e = blockIdx.x * blockDim.x + threadIdx.x;
    if (e < E) atomicAdd(&counts[dst[e]], 1);
}

__global__ void k_dinv(const int* __restrict__ counts, float* dinv, int n) {
    int i = blockIdx.x * blockDim.x + threadIdx.x;
    if (i < n) dinv[i] = rsqrtf((float)(counts[i] + 1));  // +1 self-loop
}

// --- two-level exclusive scan of PADDED counts -> row offsets -------------
__global__ void k_scan1(const int* __restrict__ counts, int* row_off,
                        int* blocksum, int n) {
    __shared__ int s[256];
    int i = blockIdx.x * 256 + threadIdx.x;
    int v = (i < n) ? ((counts[i] + 7) & ~7) : 0;   // pad rows to x8
    s[threadIdx.x] = v;
    __syncthreads();
    for (int off = 1; off < 256; off <<= 1) {
        int t = (threadIdx.x >= off) ? s[threadIdx.x - off] : 0;
        __syncthreads();
        s[threadIdx.x] += t;
        __syncthreads();
    }
    if (i < n) row_off[i + 1] = s[threadIdx.x];  // inclusive, block-local
    if (threadIdx.x == 255) blocksum[blockIdx.x] = s[255];
}

__global__ void k_scan2(const int* __restrict__ blocksum, int* blockoffs, int nb) {
    __shared__ int s[1024];
    int t = threadIdx.x;
    int v = (t < nb) ? blocksum[t] : 0;
    s[t] = v;
    __syncthreads();
    for (int off = 1; off < 1024; off <<= 1) {
        int u = (t >= off) ? s[t - off] : 0;
        __syncthreads();
        s[t] += u;
        __syncthreads();
    }
    if (t < nb) blockoffs[t] = s[t] - v;  // exclusive
}

__global__ void k_scan3(int* row_off, const int* __restrict__ blockoffs, int n) {
    int i = blockIdx.x * blockDim.x + threadIdx.x;
    if (i < n) row_off[i + 1] += blockoffs[i >> 8];
    if (i == 0) row_off[0] = 0;
}

__global__ void k_cursor(int* cursor, const int* __restrict__ row_off, int n) {
    int i = blockIdx.x * blockDim.x + threadIdx.x;
    if (i < n) cursor[i] = row_off[i];
}

// fill, XCD-bucketed: blocks with blockIdx&7==b handle only dst in bucket b,
// so each CSR region (~2.4 MB) is written from (heuristically) one XCD's L2.
__global__ void k_fill(const int* __restrict__ src, const int* __restrict__ dst,
                       const float* __restrict__ dinv, int* cursor,
                       int2* __restrict__ epack, int E, int npb) {
    const int bucket = blockIdx.x & 7;
    const int blk = blockIdx.x >> 3;
    const int nblk = gridDim.x >> 3;
    const int lo = bucket * npb, hi = lo + npb;
    for (int e = blk * 256 + threadIdx.x; e < E; e += nblk * 256) {
        int d = dst[e];
        if (d >= lo && d < hi) {
            int s = src[e];
            int pos = atomicAdd(&cursor[d], 1);
            epack[pos] = make_int2(s, __float_as_int(dinv[s]));
        }
    }
}

// write {0, 0.0f} into the pad slots [cursor[i], roff[i+1]) of each row
__global__ void k_padfill(const int* __restrict__ cursor,
                          const int* __restrict__ roff,
                          int2* __restrict__ epack, int n) {
    int i = blockIdx.x * blockDim.x + threadIdx.x;
    if (i < n) {
        int e = roff[i + 1];
        for (int k = cursor[i]; k < e; ++k) epack[k] = make_int2(0, 0);
    }
}

// --- dense h = x @ W^T ---------------------------------------------------
// Block: 256 thr = 4 waves, tile = 64 rows. x-tile staged in LDS (coalesced
// float4 global loads), W in LDS stride K+1 (per-lane b32 reads: bank =
// (lane+k)%32, conflict-free). Wave = 16 rows x 64 ch, acc[16] in regs.
// x reads are wave-uniform LDS broadcasts (no conflict).
template <int K>
__global__ __launch_bounds__(256) void k_gemm(const float* __restrict__ x,
                                              const float* __restrict__ W,
                                              float* __restrict__ h, int n) {
    __shared__ float wlds[64 * (K + 1)];
    __shared__ float xt[64 * K];
    // stage W: float4 global read, 4x b32 LDS stores (pad breaks b128 align)
    for (int idx = threadIdx.x * 4; idx < 64 * K; idx += 256 * 4) {
        int o = idx / K, k = idx - o * K;
        float4 v = *reinterpret_cast<const float4*>(W + idx);
        float* p = &wlds[o * (K + 1) + k];
        p[0] = v.x; p[1] = v.y; p[2] = v.z; p[3] = v.w;
    }
    const int row0 = blockIdx.x * 64;
    // stage x tile: 64 rows x K, coalesced float4 (clamp tail rows)
    {
        constexpr int F4 = K / 4;
        for (int idx = threadIdx.x; idx < 64 * F4; idx += 256) {
            int r = idx / F4, c = idx - r * F4;
            int rr = min(row0 + r, n - 1);
            float4 v = *reinterpret_cast<const float4*>(x + (size_t)rr * K + c * 4);
            *reinterpret_cast<float4*>(&xt[r * K + c * 4]) = v;
        }
    }
    __syncthreads();

    const int wv = threadIdx.x >> 6, lane = threadIdx.x & 63;
    const float* xrow = &xt[(wv * 16) * K];
    const float* wrow = &wlds[lane * (K + 1)];

    float acc[16];
#pragma unroll
    for (int r = 0; r < 16; ++r) acc[r] = 0.f;

#pragma unroll 4
    for (int k = 0; k < K; k += 4) {
        float w0 = wrow[k + 0], w1 = wrow[k + 1];
        float w2 = wrow[k + 2], w3 = wrow[k + 3];
#pragma unroll
        for (int r = 0; r < 16; ++r) {
            float4 a = *reinterpret_cast<const float4*>(&xrow[r * K + k]);
            acc[r] = fmaf(a.x, w0, acc[r]);
            acc[r] = fmaf(a.y, w1, acc[r]);
            acc[r] = fmaf(a.z, w2, acc[r]);
            acc[r] = fmaf(a.w, w3, acc[r]);
        }
    }
    const int rbase = row0 + wv * 16;
#pragma unroll
    for (int r = 0; r < 16; ++r) {
        if (rbase + r < n) h[(size_t)(rbase + r) * 64 + lane] = acc[r];
    }
}

// --- sparse aggregation: one wave/node, lane = channel, 8-edge ILP --------
__global__ __launch_bounds__(256) void k_agg(const float* __restrict__ h,
                                             const int* __restrict__ roff,
                                             const int2* __restrict__ epack,
                                             const float* __restrict__ dinv,
                                             const float* __restrict__ bias,
                                             float* __restrict__ out, int n,
                                             int relu) {
    int gt = blockIdx.x * blockDim.x + threadIdx.x;
    int node = gt >> 6;
    int lane = gt & 63;
    if (node >= n) return;
    float di = dinv[node];
    float hself = h[(size_t)node * 64 + lane];
    float b = bias[lane];
    int beg = roff[node], end = roff[node + 1];  // both multiples of 8
    float a0 = 0.f, a1 = 0.f, a2 = 0.f, a3 = 0.f;
    float a4 = 0.f, a5 = 0.f, a6 = 0.f, a7 = 0.f;
    for (int k = beg; k < end; k += 8) {
        const int4* p = reinterpret_cast<const int4*>(epack + k);  // 64B aligned
        int4 q0 = p[0], q1 = p[1], q2 = p[2], q3 = p[3];
        float h0 = h[(size_t)q0.x * 64 + lane];
        float h1 = h[(size_t)q0.z * 64 + lane];
        float h2 = h[(size_t)q1.x * 64 + lane];
        float h3 = h[(size_t)q1.z * 64 + lane];
        float h4 = h[(size_t)q2.x * 64 + lane];
        float h5 = h[(size_t)q2.z * 64 + lane];
        float h6 = h[(size_t)q3.x * 64 + lane];
        float h7 = h[(size_t)q3.z * 64 + lane];
        a0 = fmaf(__int_as_float(q0.y), h0, a0);
        a1 = fmaf(__int_as_float(q0.w), h1, a1);
        a2 = fmaf(__int_as_float(q1.y), h2, a2);
        a3 = fmaf(__int_as_float(q1.w), h3, a3);
        a4 = fmaf(__int_as_float(q2.y), h4, a4);
        a5 = fmaf(__int_as_float(q2.w), h5, a5);
        a6 = fmaf(__int_as_float(q3.y), h6, a6);
        a7 = fmaf(__int_as_float(q3.w), h7, a7);
    }
    float acc = (((a0 + a1) + (a2 + a3)) + ((a4 + a5) + (a6 + a7))) * di;
    acc = fmaf(di * di, hself, acc);  // self-loop
    acc += b;
    if (relu) acc = fmaxf(acc, 0.0f);
    out[(size_t)node * 64 + lane] = acc;
}

extern "C" void kernel_launch(void* const* d_in, const int* in_sizes, int n_in,
                              void* d_out, int out_size, void* d_ws, size_t ws_size,
                              hipStream_t stream) {
    const float* x  = (const float*)d_in[0];
    const int*   ei = (const int*)d_in[1];
    const float* W1 = (const float*)d_in[2];
    const float* b1 = (const float*)d_in[3];
    const float* W2 = (const float*)d_in[4];
    const float* b2 = (const float*)d_in[5];
    float* out = (float*)d_out;

    const int N = in_sizes[0] / 128;
    const int E = in_sizes[1] / 2;
    const int* src = ei;
    const int* dst = ei + E;
    const size_t Ecap = (size_t)E + 8 * (size_t)N;  // padded-CSR capacity

    char* w = (char*)d_ws;
    float* dinv  = (float*)w; w += align_up((size_t)N * 4, 256);
    int*   counts = (int*)w;  w += align_up((size_t)N * 4, 256);
    int*   roff  = (int*)w;   w += align_up(((size_t)N + 1) * 4, 256);
    int*   bsum  = (int*)w;   w += 4096;
    int*   boff  = (int*)w;   w += 4096;
    int2*  epack = (int2*)w;  w += align_up(Ecap * 8, 256);
    float* h_a   = (float*)w; w += align_up((size_t)N * 64 * 4, 256);
    int* cursor = counts;  // counts dead after scan1 -> reuse as fill cursor

    const int nbN = (N + 255) / 256;
    const int nbE = (E + 255) / 256;
    const int nbAgg = (int)(((size_t)N * 64 + 255) / 256);
    const int nbGemm = (N + 63) / 64;
    const int npb = (N + 7) / 8;  // nodes per XCD bucket

    // ---- CSR build (rows padded to x8; pads written by k_padfill) ----
    hipMemsetAsync(counts, 0, (size_t)N * 4, stream);
    k_hist<<<nbE, 256, 0, stream>>>(dst, counts, E);
    k_dinv<<<nbN, 256, 0, stream>>>(counts, dinv, N);
    k_scan1<<<nbN, 256, 0, stream>>>(counts, roff, bsum, N);
    k_scan2<<<1, 1024, 0, stream>>>(bsum, boff, nbN);
    k_scan3<<<nbN, 256, 0, stream>>>(roff, boff, N);
    k_cursor<<<nbN, 256, 0, stream>>>(cursor, roff, N);
    k_fill<<<1024, 256, 0, stream>>>(src, dst, dinv, cursor, epack, E, npb);
    k_padfill<<<nbN, 256, 0, stream>>>(cursor, roff, epack, N);

    // ---- layer 1: h_a = x @ W1^T ; d_out = relu(agg(h_a) + b1) ----
    k_gemm<128><<<nbGemm, 256, 0, stream>>>(x, W1, h_a, N);
    k_agg<<<nbAgg, 256, 0, stream>>>(h_a, roff, epack, dinv, b1, out, N, 1);

    // ---- layer 2: h_a = d_out @ W2^T ; d_out = agg(h_a) + b2 ----
    k_gemm<64><<<nbGemm, 256, 0, stream>>>(out, W2, h_a, N);
    k_agg<<<nbAgg, 256, 0, stream>>>(h_a, roff, epack, dinv, b2, out, N, 0);
}